// Round 1
// baseline (720.259 us; speedup 1.0000x reference)
//
#include <hip/hip_runtime.h>
#include <hip/hip_fp16.h>

// ---------------------------------------------------------------------------
// Problem: B=8, S=2048, D=1024, H=1024
//   q,k,v = x@W* + b*            [B,S,H]
//   P = softmax(q k^T / sqrt(H)) [B,S,S]   (output 1)
//   O = P v                      [B,S,H]   (output 0)
// d_out = [O fp32 (B*S*H) | P fp32 (B*S*S)]
// ---------------------------------------------------------------------------

typedef _Float16 half8_t __attribute__((ext_vector_type(8)));
typedef _Float16 half4_t __attribute__((ext_vector_type(4)));
typedef float    floatx4 __attribute__((ext_vector_type(4)));

__device__ __forceinline__ void async_copy16(void* lds, const void* gptr) {
    __builtin_amdgcn_global_load_lds(
        (const __attribute__((address_space(1))) void*)gptr,
        (__attribute__((address_space(3))) void*)lds,
        16, 0, 0);
}

// ---------------------------------------------------------------------------
// fp32 -> fp16 convert (vectorized)
// ---------------------------------------------------------------------------
__global__ __launch_bounds__(256)
void cvt_f32_f16(const float* __restrict__ in, _Float16* __restrict__ out, long long n4) {
    long long i = (long long)blockIdx.x * 256 + threadIdx.x;
    if (i < n4) {
        float4 v = ((const float4*)in)[i];
        half4_t h = {(_Float16)v.x, (_Float16)v.y, (_Float16)v.z, (_Float16)v.w};
        *(half4_t*)&out[i * 4] = h;
    }
}

// ---------------------------------------------------------------------------
// fp32 [R][C] -> fp16 [C][R] transpose+convert (LDS tiled)
// ---------------------------------------------------------------------------
__global__ __launch_bounds__(256)
void transpose_cvt(const float* __restrict__ in, _Float16* __restrict__ out, int R, int C) {
    __shared__ float tile[32][33];
    int c0 = blockIdx.x * 32, r0 = blockIdx.y * 32;
    int tx = threadIdx.x & 31, ty = threadIdx.x >> 5;   // 32 x 8
#pragma unroll
    for (int i = 0; i < 32; i += 8)
        tile[ty + i][tx] = in[(long long)(r0 + ty + i) * C + c0 + tx];
    __syncthreads();
#pragma unroll
    for (int i = 0; i < 32; i += 8)
        out[(long long)(c0 + ty + i) * R + r0 + tx] = (_Float16)tile[tx][ty + i];
}

// ---------------------------------------------------------------------------
// fp16 [R][C] -> fp16 [C][R] transpose, batched over z
// ---------------------------------------------------------------------------
__global__ __launch_bounds__(256)
void transpose_h(const _Float16* __restrict__ in, _Float16* __restrict__ out, int R, int C) {
    long long z = blockIdx.z;
    in  += z * (long long)R * C;
    out += z * (long long)R * C;
    __shared__ _Float16 tile[32][33];
    int c0 = blockIdx.x * 32, r0 = blockIdx.y * 32;
    int tx = threadIdx.x & 31, ty = threadIdx.x >> 5;
#pragma unroll
    for (int i = 0; i < 32; i += 8)
        tile[ty + i][tx] = in[(long long)(r0 + ty + i) * C + c0 + tx];
    __syncthreads();
#pragma unroll
    for (int i = 0; i < 32; i += 8)
        out[(long long)(c0 + ty + i) * R + r0 + tx] = tile[tx][ty + i];
}

// ---------------------------------------------------------------------------
// NT GEMM: C[m][n] = scale * sum_k A[m][k] * Bt[n][k] + bias[n]
// A: [M][K] fp16 row-major, Bt: [N][K] fp16 row-major.
// 128x128 tile, BK=32, 4 waves (2x2 of 64x64), mfma_f32_16x16x32_f16,
// global_load_lds width-16 staging (m97 structure).
// ---------------------------------------------------------------------------
template <bool OUT_HALF>
__global__ __launch_bounds__(256)
void gemm_nt(const _Float16* __restrict__ A, const _Float16* __restrict__ Bt,
             float* __restrict__ Cf, _Float16* __restrict__ Ch,
             int M, int N, int K,
             long long sA, long long sB, long long sC,
             float scale, const float* __restrict__ bias)
{
    const int z = blockIdx.z;
    A  += (long long)z * sA;
    Bt += (long long)z * sB;

    __shared__ _Float16 lA[128 * 32];
    __shared__ _Float16 lB[128 * 32];

    const int t    = threadIdx.x;
    const int lane = t & 63;
    const int wave = t >> 6;
    const int wm   = (wave >> 1) * 64;
    const int wn   = (wave & 1) * 64;
    const int fr   = lane & 15;
    const int ko   = (lane >> 4) * 8;

    const int rowBase = blockIdx.y * 128;
    const int colBase = blockIdx.x * 128;

    const _Float16* Ab = A  + (long long)rowBase * K;
    const _Float16* Bb = Bt + (long long)colBase * K;

    floatx4 acc[4][4];
#pragma unroll
    for (int i = 0; i < 4; ++i)
#pragma unroll
        for (int j = 0; j < 4; ++j)
            acc[i][j] = (floatx4){0.f, 0.f, 0.f, 0.f};

    // staging geometry: half-idx = j*2048 + t*8 ; row = idx>>5 ; col = idx&31
    const int srow = t >> 2;          // 0..63
    const int scol = (t & 3) * 8;     // 0,8,16,24
    char* la = (char*)lA;
    char* lb = (char*)lB;
    const unsigned ubase = (unsigned)wave * 1024;   // wave-uniform byte base

    for (int kt = 0; kt < K; kt += 32) {
        if (kt) __syncthreads();
        async_copy16(la + ubase,        Ab + (long long)srow        * K + kt + scol);
        async_copy16(la + 4096 + ubase, Ab + (long long)(srow + 64) * K + kt + scol);
        async_copy16(lb + ubase,        Bb + (long long)srow        * K + kt + scol);
        async_copy16(lb + 4096 + ubase, Bb + (long long)(srow + 64) * K + kt + scol);
        __syncthreads();

        half8_t af[4], bf[4];
#pragma unroll
        for (int i = 0; i < 4; ++i)
            af[i] = *(const half8_t*)&lA[(wm + i * 16 + fr) * 32 + ko];
#pragma unroll
        for (int j = 0; j < 4; ++j)
            bf[j] = *(const half8_t*)&lB[(wn + j * 16 + fr) * 32 + ko];
#pragma unroll
        for (int i = 0; i < 4; ++i)
#pragma unroll
            for (int j = 0; j < 4; ++j)
                acc[i][j] = __builtin_amdgcn_mfma_f32_16x16x32_f16(af[i], bf[j], acc[i][j], 0, 0, 0);
    }

    // epilogue: D row = (lane>>4)*4 + reg, col = lane&15  (m89-verified layout)
    const int crow0 = rowBase + wm + (lane >> 4) * 4;
    const int ccol0 = colBase + wn + fr;
#pragma unroll
    for (int j = 0; j < 4; ++j) {
        const int col = ccol0 + j * 16;
        const float bv = bias ? bias[col] : 0.f;
#pragma unroll
        for (int i = 0; i < 4; ++i) {
#pragma unroll
            for (int r = 0; r < 4; ++r) {
                const int row = crow0 + i * 16 + r;
                const float val = acc[i][j][r] * scale + bv;
                const long long off = (long long)z * sC + (long long)row * N + col;
                if (OUT_HALF) Ch[off] = (_Float16)val;
                else          Cf[off] = val;
            }
        }
    }
}

// ---------------------------------------------------------------------------
// Row softmax over S=2048 fp32, in-place; also writes fp16 copy for PV GEMM.
// One 256-thread block per row, 8 elements/thread.
// ---------------------------------------------------------------------------
__global__ __launch_bounds__(256)
void softmax_kernel(float* __restrict__ attn, _Float16* __restrict__ Ph, int S) {
    const long long row = blockIdx.x;
    float*     rp = attn + row * S;
    _Float16*  pp = Ph   + row * S;
    const int t = threadIdx.x;
    const int lane = t & 63, wave = t >> 6;

    float4 v0 = ((const float4*)rp)[t * 2];
    float4 v1 = ((const float4*)rp)[t * 2 + 1];
    float e[8] = {v0.x, v0.y, v0.z, v0.w, v1.x, v1.y, v1.z, v1.w};

    float m = e[0];
#pragma unroll
    for (int i = 1; i < 8; ++i) m = fmaxf(m, e[i]);
#pragma unroll
    for (int off = 32; off > 0; off >>= 1) m = fmaxf(m, __shfl_xor(m, off, 64));

    __shared__ float redm[4];
    __shared__ float reds[4];
    if (lane == 0) redm[wave] = m;
    __syncthreads();
    m = fmaxf(fmaxf(redm[0], redm[1]), fmaxf(redm[2], redm[3]));

    float s = 0.f;
#pragma unroll
    for (int i = 0; i < 8; ++i) { e[i] = __expf(e[i] - m); s += e[i]; }
#pragma unroll
    for (int off = 32; off > 0; off >>= 1) s += __shfl_xor(s, off, 64);
    if (lane == 0) reds[wave] = s;
    __syncthreads();
    s = reds[0] + reds[1] + reds[2] + reds[3];
    const float inv = 1.f / s;

    float4 o0 = {e[0] * inv, e[1] * inv, e[2] * inv, e[3] * inv};
    float4 o1 = {e[4] * inv, e[5] * inv, e[6] * inv, e[7] * inv};
    ((float4*)rp)[t * 2]     = o0;
    ((float4*)rp)[t * 2 + 1] = o1;

    half8_t h;
#pragma unroll
    for (int i = 0; i < 8; ++i) h[i] = (_Float16)(e[i] * inv);
    *(half8_t*)&pp[t * 8] = h;
}

// ---------------------------------------------------------------------------
extern "C" void kernel_launch(void* const* d_in, const int* in_sizes, int n_in,
                              void* d_out, int out_size, void* d_ws, size_t ws_size,
                              hipStream_t stream)
{
    const int B = 8, S = 2048, D = 1024, H = 1024;
    const float* x  = (const float*)d_in[0];
    const float* Wq = (const float*)d_in[1];
    const float* bq = (const float*)d_in[2];
    const float* Wk = (const float*)d_in[3];
    const float* bk = (const float*)d_in[4];
    const float* Wv = (const float*)d_in[5];
    const float* bv = (const float*)d_in[6];

    float* outO = (float*)d_out;                         // [B,S,H]
    float* outP = (float*)d_out + (long long)B * S * H;  // [B,S,S]

    char* ws = (char*)d_ws;
    const long long SZ_X  = (long long)B * S * D * 2;    // 33,554,432
    const long long SZ_W  = (long long)D * H * 2;        //  2,097,152
    _Float16* xh  = (_Float16*)(ws);
    _Float16* wqt = (_Float16*)(ws + SZ_X);
    _Float16* wkt = (_Float16*)(ws + SZ_X + SZ_W);
    _Float16* wvt = (_Float16*)(ws + SZ_X + 2 * SZ_W);
    _Float16* qh  = (_Float16*)(ws + SZ_X + 3 * SZ_W);
    _Float16* kh  = (_Float16*)(ws + SZ_X + 3 * SZ_W + SZ_X);
    _Float16* vh  = (_Float16*)(ws + SZ_X + 3 * SZ_W + 2 * SZ_X);
    _Float16* vt  = (_Float16*)(ws + SZ_X + 3 * SZ_W + 3 * SZ_X);
    _Float16* ph  = qh;  // P fp16 overlaps dead q/k (67 MB contiguous)

    // 1. convert x -> fp16
    {
        long long n4 = (long long)B * S * D / 4;
        cvt_f32_f16<<<(unsigned)((n4 + 255) / 256), 256, 0, stream>>>(x, xh, n4);
    }
    // 2. W transpose+convert: [D][H] fp32 -> [H][D] fp16
    {
        dim3 g(H / 32, D / 32);
        transpose_cvt<<<g, 256, 0, stream>>>(Wq, wqt, D, H);
        transpose_cvt<<<g, 256, 0, stream>>>(Wk, wkt, D, H);
        transpose_cvt<<<g, 256, 0, stream>>>(Wv, wvt, D, H);
    }
    // 3. projections: [B*S, H] = xh @ W^T  (+bias), fp16 out
    {
        dim3 g(H / 128, (B * S) / 128, 1);
        gemm_nt<true><<<g, 256, 0, stream>>>(xh, wqt, nullptr, qh, B * S, H, D, 0, 0, 0, 1.f, bq);
        gemm_nt<true><<<g, 256, 0, stream>>>(xh, wkt, nullptr, kh, B * S, H, D, 0, 0, 0, 1.f, bk);
        gemm_nt<true><<<g, 256, 0, stream>>>(xh, wvt, nullptr, vh, B * S, H, D, 0, 0, 0, 1.f, bv);
    }
    // 4. v -> v^T per batch: [S][H] -> [H][S]
    {
        dim3 g(H / 32, S / 32, B);
        transpose_h<<<g, 256, 0, stream>>>(vh, vt, S, H);
    }
    // 5. scores = q k^T / sqrt(H)  -> fp32 into attn output region
    {
        dim3 g(S / 128, S / 128, B);
        gemm_nt<false><<<g, 256, 0, stream>>>(qh, kh, outP, nullptr, S, S, H,
                                              (long long)S * H, (long long)S * H,
                                              (long long)S * S, 0.03125f, nullptr);
    }
    // 6. softmax rows, in-place + fp16 copy
    softmax_kernel<<<B * S, 256, 0, stream>>>(outP, ph, S);
    // 7. O = P v  (A = P fp16, Bt = v^T fp16) -> fp32
    {
        dim3 g(H / 128, S / 128, B);
        gemm_nt<false><<<g, 256, 0, stream>>>(ph, vt, outO, nullptr, S, H, S,
                                              (long long)S * S, (long long)H * S,
                                              (long long)S * H, 1.f, nullptr);
    }
}

// Round 5
// 623.292 us; speedup vs baseline: 1.1556x; 1.1556x over previous
//
#include <hip/hip_runtime.h>
#include <hip/hip_fp16.h>

// ---------------------------------------------------------------------------
// Problem: B=8, S=2048, D=1024, H=1024
//   q,k,v = x@W* + b*            [B,S,H]
//   P = softmax(q k^T / sqrt(H)) [B,S,S]   (output 1)
//   O = P v                      [B,S,H]   (output 0)
// d_out = [O fp32 (B*S*H) | P fp32 (B*S*S)]
// ---------------------------------------------------------------------------

typedef _Float16 half8_t __attribute__((ext_vector_type(8)));
typedef _Float16 half4_t __attribute__((ext_vector_type(4)));
typedef float    floatx4 __attribute__((ext_vector_type(4)));

__device__ __forceinline__ void async_copy16(void* lds, const void* gptr) {
    __builtin_amdgcn_global_load_lds(
        (const __attribute__((address_space(1))) void*)gptr,
        (__attribute__((address_space(3))) void*)lds,
        16, 0, 0);
}

// ---------------------------------------------------------------------------
// fp32 -> fp16 convert (vectorized)
// ---------------------------------------------------------------------------
__global__ __launch_bounds__(256)
void cvt_f32_f16(const float* __restrict__ in, _Float16* __restrict__ out, long long n4) {
    long long i = (long long)blockIdx.x * 256 + threadIdx.x;
    if (i < n4) {
        float4 v = ((const float4*)in)[i];
        half4_t h = {(_Float16)v.x, (_Float16)v.y, (_Float16)v.z, (_Float16)v.w};
        *(half4_t*)&out[i * 4] = h;
    }
}

// ---------------------------------------------------------------------------
// fp32 [R][C] -> fp16 [C][R] transpose+convert (LDS tiled)
// ---------------------------------------------------------------------------
__global__ __launch_bounds__(256)
void transpose_cvt(const float* __restrict__ in, _Float16* __restrict__ out, int R, int C) {
    __shared__ float tile[32][33];
    int c0 = blockIdx.x * 32, r0 = blockIdx.y * 32;
    int tx = threadIdx.x & 31, ty = threadIdx.x >> 5;   // 32 x 8
#pragma unroll
    for (int i = 0; i < 32; i += 8)
        tile[ty + i][tx] = in[(long long)(r0 + ty + i) * C + c0 + tx];
    __syncthreads();
#pragma unroll
    for (int i = 0; i < 32; i += 8)
        out[(long long)(c0 + ty + i) * R + r0 + tx] = (_Float16)tile[tx][ty + i];
}

// ---------------------------------------------------------------------------
// fp16 [R][C] -> fp16 [C][R] transpose, batched over z
// ---------------------------------------------------------------------------
__global__ __launch_bounds__(256)
void transpose_h(const _Float16* __restrict__ in, _Float16* __restrict__ out, int R, int C) {
    long long z = blockIdx.z;
    in  += z * (long long)R * C;
    out += z * (long long)R * C;
    __shared__ _Float16 tile[32][33];
    int c0 = blockIdx.x * 32, r0 = blockIdx.y * 32;
    int tx = threadIdx.x & 31, ty = threadIdx.x >> 5;
#pragma unroll
    for (int i = 0; i < 32; i += 8)
        tile[ty + i][tx] = in[(long long)(r0 + ty + i) * C + c0 + tx];
    __syncthreads();
#pragma unroll
    for (int i = 0; i < 32; i += 8)
        out[(long long)(c0 + ty + i) * R + r0 + tx] = tile[tx][ty + i];
}

// ---------------------------------------------------------------------------
// 256x256 8-phase NT GEMM (T1+T2+T3+T4+T5 stack).
//   C[m][n] = scale * sum_k A[m][k]*Bt[n][k] + bias[n]
// A: [M][K] fp16, Bt: [N][K] fp16. BK=64 split into two 32-wide K-panels.
// LDS: 2 buffers x (A: 2 panels x 16KB, B: 2 panels x 16KB) = 128 KiB.
// Panel layout: [256 rows][64 B], slot (16B) swizzle: s' = s ^ ((row>>1)&3).
// Stage: linear global_load_lds dest + inverse-swizzled global source.
// 8 waves: wave w owns rows (w>>2)*128 .. +128, cols (w&3)*64 .. +64.
// 4 phases/K-tile: (M-half, K-half) quadrants; vmcnt(4) at phases 1,3 only.
// ---------------------------------------------------------------------------
#define STAGE(gptr, bufB, opOff, KK, KT) {                                    \
    const _Float16* _s = (gptr) + (KT) * 64 + (KK) * 32;                      \
    char* _d = sm + (bufB) + (opOff) + (KK) * 16384 + stW;                    \
    async_copy16(_d,        _s);                                              \
    async_copy16(_d + 8192, _s + (long long)128 * K); }

#define LOAD_A(I0, KK, CB) {                                                  \
    const char* _p = sm + (CB) + (KK) * 16384 + offA0;                        \
    aq[0] = *(const half8_t*)(_p + ((I0) + 0) * 1024);                        \
    aq[1] = *(const half8_t*)(_p + ((I0) + 1) * 1024);                        \
    aq[2] = *(const half8_t*)(_p + ((I0) + 2) * 1024);                        \
    aq[3] = *(const half8_t*)(_p + ((I0) + 3) * 1024); }

#define LOAD_B(KK, CB) {                                                      \
    const char* _p = sm + (CB) + 32768 + (KK) * 16384 + offB0;                \
    bq[0] = *(const half8_t*)(_p + 0);                                        \
    bq[1] = *(const half8_t*)(_p + 1024);                                     \
    bq[2] = *(const half8_t*)(_p + 2048);                                     \
    bq[3] = *(const half8_t*)(_p + 3072); }

#define MFMA16(I0)                                                            \
    __builtin_amdgcn_s_barrier();                                             \
    __builtin_amdgcn_s_setprio(1);                                            \
    _Pragma("unroll") for (int _i = 0; _i < 4; ++_i)                          \
    _Pragma("unroll") for (int _j = 0; _j < 4; ++_j)                          \
        acc[(I0) + _i][_j] = __builtin_amdgcn_mfma_f32_16x16x32_f16(          \
            aq[_i], bq[_j], acc[(I0) + _i][_j], 0, 0, 0);                     \
    __builtin_amdgcn_s_setprio(0);                                            \
    __builtin_amdgcn_s_barrier();

template <bool OUT_HALF>
__global__ __launch_bounds__(512, 2)
void gemm256(const _Float16* __restrict__ A, const _Float16* __restrict__ Bt,
             float* __restrict__ Cf, _Float16* __restrict__ Ch,
             int N, int K,
             long long sA, long long sB, long long sC,
             float scale, const float* __restrict__ bias)
{
    __shared__ __align__(16) char smem[131072];
    char* sm = (char*)smem;

    const int z = blockIdx.z;
    const _Float16* Ao = A  + (long long)z * sA;
    const _Float16* Bo = Bt + (long long)z * sB;

    // XCD-aware bijective swizzle of the xy tile plane (m204 variant)
    const int gx = gridDim.x, nwg = gx * gridDim.y;
    int wg = blockIdx.y * gx + blockIdx.x;
    {
        int q = nwg >> 3, r = nwg & 7;
        int xcd = wg & 7, pos = wg >> 3;
        wg = (xcd < r ? xcd * (q + 1) : r * (q + 1) + (xcd - r) * q) + pos;
    }
    const int tileN = wg % gx;
    const int tileM = wg / gx;

    const int t    = threadIdx.x;
    const int lane = t & 63;
    const int w    = t >> 6;
    const int fr   = lane & 15;
    const int g    = lane >> 4;

    // fragment read byte offsets (swizzle depends only on fr -> constant/frag)
    const int swz   = ((g ^ ((fr >> 1) & 3)) << 4);
    const int offA0 = (((w >> 2) * 128 + fr) << 6) + swz;
    const int offB0 = (((w & 3) * 64 + fr) << 6) + swz;

    // stage-side geometry: lane fetches the global slot that belongs at its
    // linear LDS slot (inverse of the read swizzle; XOR = involution)
    const int srow = w * 16 + (lane >> 2);
    const int scol = (((lane & 3) ^ ((lane >> 3) & 3)) << 3);
    const _Float16* gA = Ao + (long long)(tileM * 256 + srow) * K + scol;
    const _Float16* gB = Bo + (long long)(tileN * 256 + srow) * K + scol;
    const int stW = w * 1024;

    floatx4 acc[8][4];
#pragma unroll
    for (int i = 0; i < 8; ++i)
#pragma unroll
        for (int j = 0; j < 4; ++j)
            acc[i][j] = (floatx4){0.f, 0.f, 0.f, 0.f};

    half8_t aq[4], bq[4];

    const int NT = K >> 6;

    // prologue: stage tile 0 panels in order A-k0, B-k0, A-k1, B-k1
    STAGE(gA, 0, 0,     0, 0);
    STAGE(gB, 0, 32768, 0, 0);
    STAGE(gA, 0, 0,     1, 0);
    STAGE(gB, 0, 32768, 1, 0);
    asm volatile("s_waitcnt vmcnt(4)");   // k0 panels resident, k1 in flight
    __builtin_amdgcn_s_barrier();

    for (int kt = 0; kt < NT; ++kt) {
        const int cB = (kt & 1) << 16;
        const int nB = cB ^ 65536;
        const bool more = (kt + 1) < NT;

        // phase 0: quadrant (M-half 0, K-half 0)
        LOAD_A(0, 0, cB); LOAD_B(0, cB);
        if (more) STAGE(gA, nB, 0, 0, kt + 1);
        MFMA16(0);

        // phase 1: (M-half 1, K-half 0); drain this tile's k1 panels
        LOAD_A(4, 0, cB);
        if (more) { STAGE(gB, nB, 32768, 0, kt + 1); asm volatile("s_waitcnt vmcnt(4)"); }
        else      { asm volatile("s_waitcnt vmcnt(0)"); }
        MFMA16(4);

        // phase 2: (M-half 0, K-half 1)
        LOAD_A(0, 1, cB); LOAD_B(1, cB);
        if (more) STAGE(gA, nB, 0, 1, kt + 1);
        MFMA16(0);

        // phase 3: (M-half 1, K-half 1); drain next tile's k0 panels
        LOAD_A(4, 1, cB);
        if (more) { STAGE(gB, nB, 32768, 1, kt + 1); asm volatile("s_waitcnt vmcnt(4)"); }
        MFMA16(4);
        __builtin_amdgcn_sched_barrier(0);  // pin cross-iteration motion
    }

    // epilogue: D row = g*4 + r, col = fr (m89-verified layout)
    const int orow = tileM * 256 + (w >> 2) * 128 + g * 4;
    const int ocol = tileN * 256 + (w & 3) * 64 + fr;
#pragma unroll
    for (int j = 0; j < 4; ++j) {
        const int col = ocol + j * 16;
        const float bv = bias ? bias[col] : 0.f;
#pragma unroll
        for (int i = 0; i < 8; ++i) {
#pragma unroll
            for (int r = 0; r < 4; ++r) {
                const int row = orow + i * 16 + r;
                const long long off = (long long)z * sC + (long long)row * N + col;
                const float val = acc[i][j][r] * scale + bv;
                if (OUT_HALF) Ch[off] = (_Float16)val;
                else          Cf[off] = val;
            }
        }
    }
}

// ---------------------------------------------------------------------------
// Row softmax over S=2048 fp32, in-place; also writes fp16 copy for PV GEMM.
// ---------------------------------------------------------------------------
__global__ __launch_bounds__(256)
void softmax_kernel(float* __restrict__ attn, _Float16* __restrict__ Ph, int S) {
    const long long row = blockIdx.x;
    float*     rp = attn + row * S;
    _Float16*  pp = Ph   + row * S;
    const int t = threadIdx.x;
    const int lane = t & 63, wave = t >> 6;

    float4 v0 = ((const float4*)rp)[t * 2];
    float4 v1 = ((const float4*)rp)[t * 2 + 1];
    float e[8] = {v0.x, v0.y, v0.z, v0.w, v1.x, v1.y, v1.z, v1.w};

    float m = e[0];
#pragma unroll
    for (int i = 1; i < 8; ++i) m = fmaxf(m, e[i]);
#pragma unroll
    for (int off = 32; off > 0; off >>= 1) m = fmaxf(m, __shfl_xor(m, off, 64));

    __shared__ float redm[4];
    __shared__ float reds[4];
    if (lane == 0) redm[wave] = m;
    __syncthreads();
    m = fmaxf(fmaxf(redm[0], redm[1]), fmaxf(redm[2], redm[3]));

    float s = 0.f;
#pragma unroll
    for (int i = 0; i < 8; ++i) { e[i] = __expf(e[i] - m); s += e[i]; }
#pragma unroll
    for (int off = 32; off > 0; off >>= 1) s += __shfl_xor(s, off, 64);
    if (lane == 0) reds[wave] = s;
    __syncthreads();
    s = reds[0] + reds[1] + reds[2] + reds[3];
    const float inv = 1.f / s;

    float4 o0 = {e[0] * inv, e[1] * inv, e[2] * inv, e[3] * inv};
    float4 o1 = {e[4] * inv, e[5] * inv, e[6] * inv, e[7] * inv};
    ((float4*)rp)[t * 2]     = o0;
    ((float4*)rp)[t * 2 + 1] = o1;

    half8_t h;
#pragma unroll
    for (int i = 0; i < 8; ++i) h[i] = (_Float16)(e[i] * inv);
    *(half8_t*)&pp[t * 8] = h;
}

// ---------------------------------------------------------------------------
extern "C" void kernel_launch(void* const* d_in, const int* in_sizes, int n_in,
                              void* d_out, int out_size, void* d_ws, size_t ws_size,
                              hipStream_t stream)
{
    const int B = 8, S = 2048, D = 1024, H = 1024;
    const float* x  = (const float*)d_in[0];
    const float* Wq = (const float*)d_in[1];
    const float* bq = (const float*)d_in[2];
    const float* Wk = (const float*)d_in[3];
    const float* bk = (const float*)d_in[4];
    const float* Wv = (const float*)d_in[5];
    const float* bv = (const float*)d_in[6];

    float* outO = (float*)d_out;                         // [B,S,H]
    float* outP = (float*)d_out + (long long)B * S * H;  // [B,S,S]

    char* ws = (char*)d_ws;
    const long long SZ_X  = (long long)B * S * D * 2;    // 33,554,432
    const long long SZ_W  = (long long)D * H * 2;        //  2,097,152
    _Float16* xh  = (_Float16*)(ws);
    _Float16* wqt = (_Float16*)(ws + SZ_X);
    _Float16* wkt = (_Float16*)(ws + SZ_X + SZ_W);
    _Float16* wvt = (_Float16*)(ws + SZ_X + 2 * SZ_W);
    _Float16* qh  = (_Float16*)(ws + SZ_X + 3 * SZ_W);
    _Float16* kh  = (_Float16*)(ws + SZ_X + 3 * SZ_W + SZ_X);
    _Float16* vh  = (_Float16*)(ws + SZ_X + 3 * SZ_W + 2 * SZ_X);
    _Float16* vt  = (_Float16*)(ws + SZ_X + 3 * SZ_W + 3 * SZ_X);
    _Float16* ph  = qh;  // P fp16 overlaps dead q/k (67 MB contiguous)

    // 1. convert x -> fp16
    {
        long long n4 = (long long)B * S * D / 4;
        cvt_f32_f16<<<(unsigned)((n4 + 255) / 256), 256, 0, stream>>>(x, xh, n4);
    }
    // 2. W transpose+convert: [D][H] fp32 -> [H][D] fp16
    {
        dim3 g(H / 32, D / 32);
        transpose_cvt<<<g, 256, 0, stream>>>(Wq, wqt, D, H);
        transpose_cvt<<<g, 256, 0, stream>>>(Wk, wkt, D, H);
        transpose_cvt<<<g, 256, 0, stream>>>(Wv, wvt, D, H);
    }
    // 3. projections: [B*S, H] = xh @ W^T (+bias), fp16 out
    {
        dim3 g(H / 256, (B * S) / 256, 1);
        gemm256<true><<<g, 512, 0, stream>>>(xh, wqt, nullptr, qh, H, D, 0, 0, 0, 1.f, bq);
        gemm256<true><<<g, 512, 0, stream>>>(xh, wkt, nullptr, kh, H, D, 0, 0, 0, 1.f, bk);
        gemm256<true><<<g, 512, 0, stream>>>(xh, wvt, nullptr, vh, H, D, 0, 0, 0, 1.f, bv);
    }
    // 4. v -> v^T per batch: [S][H] -> [H][S]
    {
        dim3 g(H / 32, S / 32, B);
        transpose_h<<<g, 256, 0, stream>>>(vh, vt, S, H);
    }
    // 5. scores = q k^T / sqrt(H) -> fp32 into attn output region
    {
        dim3 g(S / 256, S / 256, B);
        gemm256<false><<<g, 512, 0, stream>>>(qh, kh, outP, nullptr, S, H,
                                              (long long)S * H, (long long)S * H,
                                              (long long)S * S, 0.03125f, nullptr);
    }
    // 6. softmax rows, in-place + fp16 copy
    softmax_kernel<<<B * S, 256, 0, stream>>>(outP, ph, S);
    // 7. O = P v (A = P fp16, Bt = v^T fp16) -> fp32
    {
        dim3 g(H / 256, S / 256, B);
        gemm256<false><<<g, 512, 0, stream>>>(ph, vt, outO, nullptr, H, S,
                                              (long long)S * S, (long long)H * S,
                                              (long long)S * H, 1.f, nullptr);
    }
}

// Round 9
// 601.777 us; speedup vs baseline: 1.1969x; 1.0358x over previous
//
#include <hip/hip_runtime.h>
#include <hip/hip_fp16.h>

// ---------------------------------------------------------------------------
// Problem: B=8, S=2048, D=1024, H=1024
//   q,k,v = x@W* + b*            [B,S,H]
//   P = softmax(q k^T / sqrt(H)) [B,S,S]   (output 1)
//   O = P v                      [B,S,H]   (output 0)
// d_out = [O fp32 (B*S*H) | P fp32 (B*S*S)]
// Pipeline: cvt(x) ; W^T x3 ; fused QKV GEMM (N=3072) -> qkv[BS][3072] ;
//           v -> vt ; scores ; softmax (fp16 P into dead q|k cols) ; PV.
// ---------------------------------------------------------------------------

typedef _Float16 half8_t __attribute__((ext_vector_type(8)));
typedef _Float16 half4_t __attribute__((ext_vector_type(4)));
typedef float    floatx4 __attribute__((ext_vector_type(4)));

__device__ __forceinline__ void async_copy16(void* lds, const void* gptr) {
    __builtin_amdgcn_global_load_lds(
        (const __attribute__((address_space(1))) void*)gptr,
        (__attribute__((address_space(3))) void*)lds,
        16, 0, 0);
}

// ---------------------------------------------------------------------------
// fp32 -> fp16 convert (vectorized)
// ---------------------------------------------------------------------------
__global__ __launch_bounds__(256)
void cvt_f32_f16(const float* __restrict__ in, _Float16* __restrict__ out, long long n4) {
    long long i = (long long)blockIdx.x * 256 + threadIdx.x;
    if (i < n4) {
        float4 v = ((const float4*)in)[i];
        half4_t h = {(_Float16)v.x, (_Float16)v.y, (_Float16)v.z, (_Float16)v.w};
        *(half4_t*)&out[i * 4] = h;
    }
}

// ---------------------------------------------------------------------------
// fp32 [R][C] -> fp16 [C][R] transpose+convert (LDS tiled)
// ---------------------------------------------------------------------------
__global__ __launch_bounds__(256)
void transpose_cvt(const float* __restrict__ in, _Float16* __restrict__ out, int R, int C) {
    __shared__ float tile[32][33];
    int c0 = blockIdx.x * 32, r0 = blockIdx.y * 32;
    int tx = threadIdx.x & 31, ty = threadIdx.x >> 5;   // 32 x 8
#pragma unroll
    for (int i = 0; i < 32; i += 8)
        tile[ty + i][tx] = in[(long long)(r0 + ty + i) * C + c0 + tx];
    __syncthreads();
#pragma unroll
    for (int i = 0; i < 32; i += 8)
        out[(long long)(c0 + ty + i) * R + r0 + tx] = (_Float16)tile[tx][ty + i];
}

// ---------------------------------------------------------------------------
// fp16 [R][C] -> [C][R] transpose, 64x64 tiles.
// Global: 16B/lane both sides (coalesced). LDS: scalar 2B ops only —
// alignment-safe (b128 LDS at stride 132B was the round-6 fault suspect).
// ---------------------------------------------------------------------------
__global__ __launch_bounds__(256)
void transpose_h64(const _Float16* __restrict__ in, long long zin, int ldin,
                   _Float16* __restrict__ out, long long zout, int ldout) {
    const long long z = blockIdx.z;
    in  += z * zin;
    out += z * zout;
    __shared__ _Float16 tile[64][66];
    const int t  = threadIdx.x;
    const int r0 = blockIdx.y * 64, c0 = blockIdx.x * 64;
    const int col8 = (t & 7) * 8;
    const int row  = t >> 3;                 // 0..31
#pragma unroll
    for (int p = 0; p < 2; ++p) {
        const int r = row + p * 32;
        half8_t v = *(const half8_t*)&in[(long long)(r0 + r) * ldin + c0 + col8];
#pragma unroll
        for (int i = 0; i < 8; ++i) tile[r][col8 + i] = v[i];
    }
    __syncthreads();
    const int c  = t >> 3;                   // 0..31
    const int rb = (t & 7) * 8;              // 0,8,..,56
#pragma unroll
    for (int p = 0; p < 2; ++p) {
        const int cc = c + p * 32;
        half8_t v;
#pragma unroll
        for (int i = 0; i < 8; ++i) v[i] = tile[rb + i][cc];
        *(half8_t*)&out[(long long)(c0 + cc) * ldout + r0 + rb] = v;
    }
}

// ---------------------------------------------------------------------------
// 256x256 8-phase NT GEMM (T1+T2+T3+T4+T5 stack), strided operands.
//   C[m][n] = scale * sum_k A[m][k]*Bt[n][k] (+ segmented bias)
// BK=64 as two 32-wide K-panels; LDS 128 KiB (2 dbuf x (A,B) x 2 panels).
// Panel [256 rows][64 B]; 16B-slot swizzle s' = s ^ ((row>>1)&3), applied on
// BOTH the ds_read addr and the pre-swizzled global source (involution).
// 8 waves (2M x 4N), per-wave 128x64 out. vmcnt(4) at phases 1,3 only.
// ---------------------------------------------------------------------------
#define STAGE(gptr, LD, bufB, opOff, KK, KT) {                                \
    const _Float16* _s = (gptr) + (KT) * 64 + (KK) * 32;                      \
    char* _d = sm + (bufB) + (opOff) + (KK) * 16384 + stW;                    \
    async_copy16(_d,        _s);                                              \
    async_copy16(_d + 8192, _s + (long long)128 * (LD)); }

#define LOAD_A(I0, KK, CB) {                                                  \
    const char* _p = sm + (CB) + (KK) * 16384 + offA0;                        \
    aq[0] = *(const half8_t*)(_p + ((I0) + 0) * 1024);                        \
    aq[1] = *(const half8_t*)(_p + ((I0) + 1) * 1024);                        \
    aq[2] = *(const half8_t*)(_p + ((I0) + 2) * 1024);                        \
    aq[3] = *(const half8_t*)(_p + ((I0) + 3) * 1024); }

#define LOAD_B(KK, CB) {                                                      \
    const char* _p = sm + (CB) + 32768 + (KK) * 16384 + offB0;                \
    bq[0] = *(const half8_t*)(_p + 0);                                        \
    bq[1] = *(const half8_t*)(_p + 1024);                                     \
    bq[2] = *(const half8_t*)(_p + 2048);                                     \
    bq[3] = *(const half8_t*)(_p + 3072); }

#define MFMA16(I0)                                                            \
    __builtin_amdgcn_s_barrier();                                             \
    __builtin_amdgcn_s_setprio(1);                                            \
    _Pragma("unroll") for (int _i = 0; _i < 4; ++_i)                          \
    _Pragma("unroll") for (int _j = 0; _j < 4; ++_j)                          \
        acc[(I0) + _i][_j] = __builtin_amdgcn_mfma_f32_16x16x32_f16(          \
            aq[_i], bq[_j], acc[(I0) + _i][_j], 0, 0, 0);                     \
    __builtin_amdgcn_s_setprio(0);                                            \
    __builtin_amdgcn_s_barrier();

template <bool OUT_HALF>
__global__ __launch_bounds__(512, 2)
void gemm256(const _Float16* __restrict__ A, const _Float16* __restrict__ Bt,
             float* __restrict__ Cf, _Float16* __restrict__ Ch,
             int K, int ldA, int ldB, int ldC,
             long long sA, long long sB, long long sC,
             float scale,
             const float* __restrict__ b0, const float* __restrict__ b1,
             const float* __restrict__ b2)
{
    __shared__ __align__(16) char smem[131072];
    char* sm = (char*)smem;

    const int z = blockIdx.z;
    const _Float16* Ao = A  + (long long)z * sA;
    const _Float16* Bo = Bt + (long long)z * sB;

    // XCD-aware bijective swizzle of the xy tile plane (m204 variant)
    const int gx = gridDim.x, nwg = gx * gridDim.y;
    int wg = blockIdx.y * gx + blockIdx.x;
    {
        int q = nwg >> 3, r = nwg & 7;
        int xcd = wg & 7, pos = wg >> 3;
        wg = (xcd < r ? xcd * (q + 1) : r * (q + 1) + (xcd - r) * q) + pos;
    }
    const int tileN = wg % gx;
    const int tileM = wg / gx;

    const int t    = threadIdx.x;
    const int lane = t & 63;
    const int w    = t >> 6;
    const int fr   = lane & 15;
    const int g    = lane >> 4;

    // fragment read byte offsets (swizzled)
    const int swz   = ((g ^ ((fr >> 1) & 3)) << 4);
    const int offA0 = (((w >> 2) * 128 + fr) << 6) + swz;
    const int offB0 = (((w & 3) * 64 + fr) << 6) + swz;

    // stage-side: pre-swizzled global source (XOR involution of read swizzle)
    const int srow = w * 16 + (lane >> 2);
    const int scol = (((lane & 3) ^ ((lane >> 3) & 3)) << 3);
    const _Float16* gA = Ao + (long long)(tileM * 256 + srow) * ldA + scol;
    const _Float16* gB = Bo + (long long)(tileN * 256 + srow) * ldB + scol;
    const int stW = w * 1024;

    floatx4 acc[8][4];
#pragma unroll
    for (int i = 0; i < 8; ++i)
#pragma unroll
        for (int j = 0; j < 4; ++j)
            acc[i][j] = (floatx4){0.f, 0.f, 0.f, 0.f};

    half8_t aq[4], bq[4];

    const int NT = K >> 6;

    // prologue: stage tile 0 panels
    STAGE(gA, ldA, 0, 0,     0, 0);
    STAGE(gB, ldB, 0, 32768, 0, 0);
    STAGE(gA, ldA, 0, 0,     1, 0);
    STAGE(gB, ldB, 0, 32768, 1, 0);
    asm volatile("s_waitcnt vmcnt(4)");   // k0 panels resident, k1 in flight
    __builtin_amdgcn_s_barrier();

    for (int kt = 0; kt < NT; ++kt) {
        const int cB = (kt & 1) << 16;
        const int nB = cB ^ 65536;
        const bool more = (kt + 1) < NT;

        // phase 0: (M-half 0, K-half 0)
        LOAD_A(0, 0, cB); LOAD_B(0, cB);
        if (more) STAGE(gA, ldA, nB, 0, 0, kt + 1);
        MFMA16(0);

        // phase 1: (M-half 1, K-half 0); drain this tile's k1 panels
        LOAD_A(4, 0, cB);
        if (more) { STAGE(gB, ldB, nB, 32768, 0, kt + 1); asm volatile("s_waitcnt vmcnt(4)"); }
        else      { asm volatile("s_waitcnt vmcnt(0)"); }
        MFMA16(4);

        // phase 2: (M-half 0, K-half 1)
        LOAD_A(0, 1, cB); LOAD_B(1, cB);
        if (more) STAGE(gA, ldA, nB, 0, 1, kt + 1);
        MFMA16(0);

        // phase 3: (M-half 1, K-half 1); drain next tile's k0 panels
        LOAD_A(4, 1, cB);
        if (more) { STAGE(gB, ldB, nB, 32768, 1, kt + 1); asm volatile("s_waitcnt vmcnt(4)"); }
        MFMA16(4);
        __builtin_amdgcn_sched_barrier(0);
    }

    // epilogue: D row = g*4 + r, col = fr (m89-verified layout)
    const int orow = tileM * 256 + (w >> 2) * 128 + g * 4;
    const int ocol = tileN * 256 + (w & 3) * 64 + fr;
#pragma unroll
    for (int j = 0; j < 4; ++j) {
        const int col = ocol + j * 16;
        float bv = 0.f;
        if (b0) bv = col < 1024 ? b0[col] : (col < 2048 ? b1[col - 1024] : b2[col - 2048]);
#pragma unroll
        for (int i = 0; i < 8; ++i) {
#pragma unroll
            for (int r = 0; r < 4; ++r) {
                const int row = orow + i * 16 + r;
                const long long off = (long long)z * sC + (long long)row * ldC + col;
                const float val = acc[i][j][r] * scale + bv;
                if (OUT_HALF) Ch[off] = (_Float16)val;
                else          Cf[off] = val;
            }
        }
    }
}

// ---------------------------------------------------------------------------
// Row softmax over S=2048 fp32 in-place; fp16 copy at row stride ldP.
// ---------------------------------------------------------------------------
__global__ __launch_bounds__(256)
void softmax_kernel(float* __restrict__ attn, _Float16* __restrict__ Ph,
                    int S, int ldP) {
    const long long row = blockIdx.x;
    float*     rp = attn + row * S;
    _Float16*  pp = Ph   + row * (long long)ldP;
    const int t = threadIdx.x;
    const int lane = t & 63, wave = t >> 6;

    float4 v0 = ((const float4*)rp)[t * 2];
    float4 v1 = ((const float4*)rp)[t * 2 + 1];
    float e[8] = {v0.x, v0.y, v0.z, v0.w, v1.x, v1.y, v1.z, v1.w};

    float m = e[0];
#pragma unroll
    for (int i = 1; i < 8; ++i) m = fmaxf(m, e[i]);
#pragma unroll
    for (int off = 32; off > 0; off >>= 1) m = fmaxf(m, __shfl_xor(m, off, 64));

    __shared__ float redm[4];
    __shared__ float reds[4];
    if (lane == 0) redm[wave] = m;
    __syncthreads();
    m = fmaxf(fmaxf(redm[0], redm[1]), fmaxf(redm[2], redm[3]));

    float s = 0.f;
#pragma unroll
    for (int i = 0; i < 8; ++i) { e[i] = __expf(e[i] - m); s += e[i]; }
#pragma unroll
    for (int off = 32; off > 0; off >>= 1) s += __shfl_xor(s, off, 64);
    if (lane == 0) reds[wave] = s;
    __syncthreads();
    s = reds[0] + reds[1] + reds[2] + reds[3];
    const float inv = 1.f / s;

    float4 o0 = {e[0] * inv, e[1] * inv, e[2] * inv, e[3] * inv};
    float4 o1 = {e[4] * inv, e[5] * inv, e[6] * inv, e[7] * inv};
    ((float4*)rp)[t * 2]     = o0;
    ((float4*)rp)[t * 2 + 1] = o1;

    half8_t h;
#pragma unroll
    for (int i = 0; i < 8; ++i) h[i] = (_Float16)(e[i] * inv);
    *(half8_t*)&pp[t * 8] = h;
}

// ---------------------------------------------------------------------------
extern "C" void kernel_launch(void* const* d_in, const int* in_sizes, int n_in,
                              void* d_out, int out_size, void* d_ws, size_t ws_size,
                              hipStream_t stream)
{
    const int B = 8, S = 2048, D = 1024, H = 1024;
    const int N3 = 3 * H;                     // 3072
    const float* x  = (const float*)d_in[0];
    const float* Wq = (const float*)d_in[1];
    const float* bq = (const float*)d_in[2];
    const float* Wk = (const float*)d_in[3];
    const float* bk = (const float*)d_in[4];
    const float* Wv = (const float*)d_in[5];
    const float* bv = (const float*)d_in[6];

    float* outO = (float*)d_out;                         // [B,S,H]
    float* outP = (float*)d_out + (long long)B * S * H;  // [B,S,S]

    char* ws = (char*)d_ws;
    const long long SZ_XH   = (long long)B * S * D * 2;       // 33.5 MB
    const long long SZ_W3   = (long long)N3 * D * 2;          //  6.3 MB
    const long long SZ_QKV  = (long long)B * S * N3 * 2;      // 100.7 MB
    _Float16* xh    = (_Float16*)(ws);
    _Float16* wqkvt = (_Float16*)(ws + SZ_XH);                        // [3072][1024]
    _Float16* qkv   = (_Float16*)(ws + SZ_XH + SZ_W3);                // [B*S][3072]
    _Float16* vt    = (_Float16*)(ws + SZ_XH + SZ_W3 + SZ_QKV);      // [B][H][S]

    // 1. x -> fp16
    {
        long long n4 = (long long)B * S * D / 4;
        cvt_f32_f16<<<(unsigned)((n4 + 255) / 256), 256, 0, stream>>>(x, xh, n4);
    }
    // 2. weights: [D][H] fp32 -> [H][D] fp16, concatenated [3072][1024]
    {
        dim3 g(H / 32, D / 32);
        transpose_cvt<<<g, 256, 0, stream>>>(Wq, wqkvt,             D, H);
        transpose_cvt<<<g, 256, 0, stream>>>(Wk, wqkvt + (long long)H * D,     D, H);
        transpose_cvt<<<g, 256, 0, stream>>>(Wv, wqkvt + (long long)2 * H * D, D, H);
    }
    // 3. fused QKV projection: [B*S,3072] = xh @ Wqkv^T + b
    {
        dim3 g(N3 / 256, (B * S) / 256, 1);
        gemm256<true><<<g, 512, 0, stream>>>(xh, wqkvt, nullptr, qkv,
                                             D, D, D, N3, 0, 0, 0, 1.f, bq, bk, bv);
    }
    // 4. v slice -> vt [H][S] per batch
    {
        dim3 g(H / 64, S / 64, B);
        transpose_h64<<<g, 256, 0, stream>>>(qkv + 2 * H, (long long)S * N3, N3,
                                             vt, (long long)H * S, S);
    }
    // 5. scores = q k^T / 32 -> fp32 P
    {
        dim3 g(S / 256, S / 256, B);
        gemm256<false><<<g, 512, 0, stream>>>(qkv, qkv + H, outP, nullptr,
                                              D, N3, N3, S,
                                              (long long)S * N3, (long long)S * N3,
                                              (long long)S * S, 0.03125f,
                                              nullptr, nullptr, nullptr);
    }
    // 6. softmax rows; fp16 P overwrites dead q|k columns of qkv
    softmax_kernel<<<B * S, 256, 0, stream>>>(outP, qkv, S, N3);
    // 7. O = P v
    {
        dim3 g(H / 256, S / 256, B);
        gemm256<false><<<g, 512, 0, stream>>>(qkv, vt, outO, nullptr,
                                              S, N3, S, H,
                                              (long long)S * N3, (long long)H * S,
                                              (long long)S * H, 1.f,
                                              nullptr, nullptr, nullptr);
    }
}

// Round 10
// 571.959 us; speedup vs baseline: 1.2593x; 1.0521x over previous
//
#include <hip/hip_runtime.h>
#include <hip/hip_fp16.h>

// ---------------------------------------------------------------------------
// Problem: B=8, S=2048, D=1024, H=1024
//   q,k,v = x@W* + b*            [B,S,H]
//   P = softmax(q k^T / sqrt(H)) [B,S,S]   (output 1)
//   O = P v                      [B,S,H]   (output 0)
// d_out = [O fp32 (B*S*H) | P fp32 (B*S*S)]
// Pipeline: cvt(x) ; W^T x3 ; fused QKV GEMM (N=3072) -> qkv[BS][3072] ;
//           v -> vt ; scores ; softmax (fp16 P into dead q|k cols) ; PV.
// ---------------------------------------------------------------------------

typedef _Float16 half8_t __attribute__((ext_vector_type(8)));
typedef _Float16 half4_t __attribute__((ext_vector_type(4)));
typedef float    floatx4 __attribute__((ext_vector_type(4)));

__device__ __forceinline__ void async_copy16(void* lds, const void* gptr) {
    __builtin_amdgcn_global_load_lds(
        (const __attribute__((address_space(1))) void*)gptr,
        (__attribute__((address_space(3))) void*)lds,
        16, 0, 0);
}

// ---------------------------------------------------------------------------
// fp32 -> fp16 convert (vectorized)
// ---------------------------------------------------------------------------
__global__ __launch_bounds__(256)
void cvt_f32_f16(const float* __restrict__ in, _Float16* __restrict__ out, long long n4) {
    long long i = (long long)blockIdx.x * 256 + threadIdx.x;
    if (i < n4) {
        float4 v = ((const float4*)in)[i];
        half4_t h = {(_Float16)v.x, (_Float16)v.y, (_Float16)v.z, (_Float16)v.w};
        *(half4_t*)&out[i * 4] = h;
    }
}

// ---------------------------------------------------------------------------
// fp32 [R][C] -> fp16 [C][R] transpose+convert (LDS tiled)
// ---------------------------------------------------------------------------
__global__ __launch_bounds__(256)
void transpose_cvt(const float* __restrict__ in, _Float16* __restrict__ out, int R, int C) {
    __shared__ float tile[32][33];
    int c0 = blockIdx.x * 32, r0 = blockIdx.y * 32;
    int tx = threadIdx.x & 31, ty = threadIdx.x >> 5;   // 32 x 8
#pragma unroll
    for (int i = 0; i < 32; i += 8)
        tile[ty + i][tx] = in[(long long)(r0 + ty + i) * C + c0 + tx];
    __syncthreads();
#pragma unroll
    for (int i = 0; i < 32; i += 8)
        out[(long long)(c0 + ty + i) * R + r0 + tx] = (_Float16)tile[tx][ty + i];
}

// ---------------------------------------------------------------------------
// fp16 [R][C] -> [C][R] transpose, 64x64 tiles.
// Global: 16B/lane both sides (coalesced). LDS: scalar 2B ops only.
// ---------------------------------------------------------------------------
__global__ __launch_bounds__(256)
void transpose_h64(const _Float16* __restrict__ in, long long zin, int ldin,
                   _Float16* __restrict__ out, long long zout, int ldout) {
    const long long z = blockIdx.z;
    in  += z * zin;
    out += z * zout;
    __shared__ _Float16 tile[64][66];
    const int t  = threadIdx.x;
    const int r0 = blockIdx.y * 64, c0 = blockIdx.x * 64;
    const int col8 = (t & 7) * 8;
    const int row  = t >> 3;                 // 0..31
#pragma unroll
    for (int p = 0; p < 2; ++p) {
        const int r = row + p * 32;
        half8_t v = *(const half8_t*)&in[(long long)(r0 + r) * ldin + c0 + col8];
#pragma unroll
        for (int i = 0; i < 8; ++i) tile[r][col8 + i] = v[i];
    }
    __syncthreads();
    const int c  = t >> 3;                   // 0..31
    const int rb = (t & 7) * 8;              // 0,8,..,56
#pragma unroll
    for (int p = 0; p < 2; ++p) {
        const int cc = c + p * 32;
        half8_t v;
#pragma unroll
        for (int i = 0; i < 8; ++i) v[i] = tile[rb + i][cc];
        *(half8_t*)&out[(long long)(c0 + cc) * ldout + r0 + rb] = v;
    }
}

// ---------------------------------------------------------------------------
// 256x256 8-phase NT GEMM (T1+T2+T3+T4+T5 stack), strided operands.
//   C[m][n] = scale * sum_k A[m][k]*Bt[n][k] (+ segmented bias)
// BK=64 as two 32-wide K-panels; staging LDS 128 KiB (2 dbuf x (A,B) x 2).
// Panel [256 rows][64 B]; 16B-slot swizzle s' = s ^ ((row>>1)&3) on BOTH the
// ds_read addr and the pre-swizzled global source (involution).
// 8 waves (2M x 4N), per-wave 128x64 out. vmcnt(4) at phases 1,3 only.
// OUT_HALF epilogue: LDS-staged (wave-private [128][68] fp16, stride 68 ->
// 2-way-free banks) then 16B/lane coalesced stores — fixes the 2x HBM write
// amplification measured in r9 (WRITE_SIZE 200 MB for 100 MB of fp16 C).
// ---------------------------------------------------------------------------
#define STAGE(gptr, LD, bufB, opOff, KK, KT) {                                \
    const _Float16* _s = (gptr) + (KT) * 64 + (KK) * 32;                      \
    char* _d = sm + (bufB) + (opOff) + (KK) * 16384 + stW;                    \
    async_copy16(_d,        _s);                                              \
    async_copy16(_d + 8192, _s + (long long)128 * (LD)); }

#define LOAD_A(I0, KK, CB) {                                                  \
    const char* _p = sm + (CB) + (KK) * 16384 + offA0;                        \
    aq[0] = *(const half8_t*)(_p + ((I0) + 0) * 1024);                        \
    aq[1] = *(const half8_t*)(_p + ((I0) + 1) * 1024);                        \
    aq[2] = *(const half8_t*)(_p + ((I0) + 2) * 1024);                        \
    aq[3] = *(const half8_t*)(_p + ((I0) + 3) * 1024); }

#define LOAD_B(KK, CB) {                                                      \
    const char* _p = sm + (CB) + 32768 + (KK) * 16384 + offB0;                \
    bq[0] = *(const half8_t*)(_p + 0);                                        \
    bq[1] = *(const half8_t*)(_p + 1024);                                     \
    bq[2] = *(const half8_t*)(_p + 2048);                                     \
    bq[3] = *(const half8_t*)(_p + 3072); }

#define MFMA16(I0)                                                            \
    __builtin_amdgcn_s_barrier();                                             \
    __builtin_amdgcn_s_setprio(1);                                            \
    _Pragma("unroll") for (int _i = 0; _i < 4; ++_i)                          \
    _Pragma("unroll") for (int _j = 0; _j < 4; ++_j)                          \
        acc[(I0) + _i][_j] = __builtin_amdgcn_mfma_f32_16x16x32_f16(          \
            aq[_i], bq[_j], acc[(I0) + _i][_j], 0, 0, 0);                     \
    __builtin_amdgcn_s_setprio(0);                                            \
    __builtin_amdgcn_s_barrier();

template <bool OUT_HALF>
__global__ __launch_bounds__(512, 2)
void gemm256(const _Float16* __restrict__ A, const _Float16* __restrict__ Bt,
             float* __restrict__ Cf, _Float16* __restrict__ Ch,
             int K, int ldA, int ldB, int ldC,
             long long sA, long long sB, long long sC,
             float scale,
             const float* __restrict__ b0, const float* __restrict__ b1,
             const float* __restrict__ b2)
{
    // staging uses [0, 131072); OUT_HALF epilogue reuses [0, 139264) as
    // 8 wave-private [128][68] fp16 regions (17408 B each).
    __shared__ __align__(16) char smem[139264];
    char* sm = (char*)smem;

    const int z = blockIdx.z;
    const _Float16* Ao = A  + (long long)z * sA;
    const _Float16* Bo = Bt + (long long)z * sB;

    // XCD-aware bijective swizzle of the xy tile plane (m204 variant)
    const int gx = gridDim.x, nwg = gx * gridDim.y;
    int wg = blockIdx.y * gx + blockIdx.x;
    {
        int q = nwg >> 3, r = nwg & 7;
        int xcd = wg & 7, pos = wg >> 3;
        wg = (xcd < r ? xcd * (q + 1) : r * (q + 1) + (xcd - r) * q) + pos;
    }
    const int tileN = wg % gx;
    const int tileM = wg / gx;

    const int t    = threadIdx.x;
    const int lane = t & 63;
    const int w    = t >> 6;
    const int fr   = lane & 15;
    const int g    = lane >> 4;

    // fragment read byte offsets (swizzled)
    const int swz   = ((g ^ ((fr >> 1) & 3)) << 4);
    const int offA0 = (((w >> 2) * 128 + fr) << 6) + swz;
    const int offB0 = (((w & 3) * 64 + fr) << 6) + swz;

    // stage-side: pre-swizzled global source (XOR involution of read swizzle)
    const int srow = w * 16 + (lane >> 2);
    const int scol = (((lane & 3) ^ ((lane >> 3) & 3)) << 3);
    const _Float16* gA = Ao + (long long)(tileM * 256 + srow) * ldA + scol;
    const _Float16* gB = Bo + (long long)(tileN * 256 + srow) * ldB + scol;
    const int stW = w * 1024;

    floatx4 acc[8][4];
#pragma unroll
    for (int i = 0; i < 8; ++i)
#pragma unroll
        for (int j = 0; j < 4; ++j)
            acc[i][j] = (floatx4){0.f, 0.f, 0.f, 0.f};

    half8_t aq[4], bq[4];

    const int NT = K >> 6;

    // prologue: stage tile 0 panels
    STAGE(gA, ldA, 0, 0,     0, 0);
    STAGE(gB, ldB, 0, 32768, 0, 0);
    STAGE(gA, ldA, 0, 0,     1, 0);
    STAGE(gB, ldB, 0, 32768, 1, 0);
    asm volatile("s_waitcnt vmcnt(4)");   // k0 panels resident, k1 in flight
    __builtin_amdgcn_s_barrier();

    for (int kt = 0; kt < NT; ++kt) {
        const int cB = (kt & 1) << 16;
        const int nB = cB ^ 65536;
        const bool more = (kt + 1) < NT;

        // phase 0: (M-half 0, K-half 0)
        LOAD_A(0, 0, cB); LOAD_B(0, cB);
        if (more) STAGE(gA, ldA, nB, 0, 0, kt + 1);
        MFMA16(0);

        // phase 1: (M-half 1, K-half 0); drain this tile's k1 panels
        LOAD_A(4, 0, cB);
        if (more) { STAGE(gB, ldB, nB, 32768, 0, kt + 1); asm volatile("s_waitcnt vmcnt(4)"); }
        else      { asm volatile("s_waitcnt vmcnt(0)"); }
        MFMA16(4);

        // phase 2: (M-half 0, K-half 1)
        LOAD_A(0, 1, cB); LOAD_B(1, cB);
        if (more) STAGE(gA, ldA, nB, 0, 1, kt + 1);
        MFMA16(0);

        // phase 3: (M-half 1, K-half 1); drain next tile's k0 panels
        LOAD_A(4, 1, cB);
        if (more) { STAGE(gB, ldB, nB, 32768, 1, kt + 1); asm volatile("s_waitcnt vmcnt(4)"); }
        MFMA16(4);
        __builtin_amdgcn_sched_barrier(0);
    }

    // epilogue: D row = g*4 + r, col = fr (m89-verified layout)
    const int orow = tileM * 256 + (w >> 2) * 128 + g * 4;
    const int ocol = tileN * 256 + (w & 3) * 64 + fr;

    if (OUT_HALF) {
        // --- LDS-staged coalesced fp16 store ---
        _Float16* lw = (_Float16*)(sm + (size_t)w * 17408);   // [128][68]
#pragma unroll
        for (int j = 0; j < 4; ++j) {
            const int col = ocol + j * 16;
            const float bv = b0 ? (col < 1024 ? b0[col]
                               : (col < 2048 ? b1[col - 1024] : b2[col - 2048]))
                               : 0.f;
#pragma unroll
            for (int i = 0; i < 8; ++i) {
#pragma unroll
                for (int r = 0; r < 4; ++r) {
                    const int rl = i * 16 + g * 4 + r;
                    lw[rl * 68 + j * 16 + fr] = (_Float16)(acc[i][j][r] * scale + bv);
                }
            }
        }
        __syncthreads();   // order LDS writes before cross-lane readback
        const int rr = lane >> 3;          // 0..7
        const int c8 = (lane & 7) * 8;     // 0,8,...,56
        const int grow0 = tileM * 256 + (w >> 2) * 128;
        const int gcol0 = tileN * 256 + (w & 3) * 64 + c8;
#pragma unroll
        for (int rg = 0; rg < 16; ++rg) {
            const int rl = rg * 8 + rr;
            half4_t lo = *(const half4_t*)&lw[rl * 68 + c8];
            half4_t hi = *(const half4_t*)&lw[rl * 68 + c8 + 4];
            half8_t v = {lo[0], lo[1], lo[2], lo[3], hi[0], hi[1], hi[2], hi[3]};
            const long long off = (long long)z * sC + (long long)(grow0 + rl) * ldC + gcol0;
            *(half8_t*)&Ch[off] = v;
        }
    } else {
        // fp32 path: 16 lanes x 4B = 64B sector-aligned segments — no
        // amplification measured; keep direct stores.
#pragma unroll
        for (int j = 0; j < 4; ++j) {
            const int col = ocol + j * 16;
            float bv = 0.f;
            if (b0) bv = col < 1024 ? b0[col] : (col < 2048 ? b1[col - 1024] : b2[col - 2048]);
#pragma unroll
            for (int i = 0; i < 8; ++i) {
#pragma unroll
                for (int r = 0; r < 4; ++r) {
                    const int row = orow + i * 16 + r;
                    const long long off = (long long)z * sC + (long long)row * ldC + col;
                    Cf[off] = acc[i][j][r] * scale + bv;
                }
            }
        }
    }
}

// ---------------------------------------------------------------------------
// Row softmax over S=2048 fp32 in-place; fp16 copy at row stride ldP.
// ---------------------------------------------------------------------------
__global__ __launch_bounds__(256)
void softmax_kernel(float* __restrict__ attn, _Float16* __restrict__ Ph,
                    int S, int ldP) {
    const long long row = blockIdx.x;
    float*     rp = attn + row * S;
    _Float16*  pp = Ph   + row * (long long)ldP;
    const int t = threadIdx.x;
    const int lane = t & 63, wave = t >> 6;

    float4 v0 = ((const float4*)rp)[t * 2];
    float4 v1 = ((const float4*)rp)[t * 2 + 1];
    float e[8] = {v0.x, v0.y, v0.z, v0.w, v1.x, v1.y, v1.z, v1.w};

    float m = e[0];
#pragma unroll
    for (int i = 1; i < 8; ++i) m = fmaxf(m, e[i]);
#pragma unroll
    for (int off = 32; off > 0; off >>= 1) m = fmaxf(m, __shfl_xor(m, off, 64));

    __shared__ float redm[4];
    __shared__ float reds[4];
    if (lane == 0) redm[wave] = m;
    __syncthreads();
    m = fmaxf(fmaxf(redm[0], redm[1]), fmaxf(redm[2], redm[3]));

    float s = 0.f;
#pragma unroll
    for (int i = 0; i < 8; ++i) { e[i] = __expf(e[i] - m); s += e[i]; }
#pragma unroll
    for (int off = 32; off > 0; off >>= 1) s += __shfl_xor(s, off, 64);
    if (lane == 0) reds[wave] = s;
    __syncthreads();
    s = reds[0] + reds[1] + reds[2] + reds[3];
    const float inv = 1.f / s;

    float4 o0 = {e[0] * inv, e[1] * inv, e[2] * inv, e[3] * inv};
    float4 o1 = {e[4] * inv, e[5] * inv, e[6] * inv, e[7] * inv};
    ((float4*)rp)[t * 2]     = o0;
    ((float4*)rp)[t * 2 + 1] = o1;

    half8_t h;
#pragma unroll
    for (int i = 0; i < 8; ++i) h[i] = (_Float16)(e[i] * inv);
    *(half8_t*)&pp[t * 8] = h;
}

// ---------------------------------------------------------------------------
extern "C" void kernel_launch(void* const* d_in, const int* in_sizes, int n_in,
                              void* d_out, int out_size, void* d_ws, size_t ws_size,
                              hipStream_t stream)
{
    const int B = 8, S = 2048, D = 1024, H = 1024;
    const int N3 = 3 * H;                     // 3072
    const float* x  = (const float*)d_in[0];
    const float* Wq = (const float*)d_in[1];
    const float* bq = (const float*)d_in[2];
    const float* Wk = (const float*)d_in[3];
    const float* bk = (const float*)d_in[4];
    const float* Wv = (const float*)d_in[5];
    const float* bv = (const float*)d_in[6];

    float* outO = (float*)d_out;                         // [B,S,H]
    float* outP = (float*)d_out + (long long)B * S * H;  // [B,S,S]

    char* ws = (char*)d_ws;
    const long long SZ_XH   = (long long)B * S * D * 2;       // 33.5 MB
    const long long SZ_W3   = (long long)N3 * D * 2;          //  6.3 MB
    const long long SZ_QKV  = (long long)B * S * N3 * 2;      // 100.7 MB
    _Float16* xh    = (_Float16*)(ws);
    _Float16* wqkvt = (_Float16*)(ws + SZ_XH);                        // [3072][1024]
    _Float16* qkv   = (_Float16*)(ws + SZ_XH + SZ_W3);                // [B*S][3072]
    _Float16* vt    = (_Float16*)(ws + SZ_XH + SZ_W3 + SZ_QKV);      // [B][H][S]

    // 1. x -> fp16
    {
        long long n4 = (long long)B * S * D / 4;
        cvt_f32_f16<<<(unsigned)((n4 + 255) / 256), 256, 0, stream>>>(x, xh, n4);
    }
    // 2. weights: [D][H] fp32 -> [H][D] fp16, concatenated [3072][1024]
    {
        dim3 g(H / 32, D / 32);
        transpose_cvt<<<g, 256, 0, stream>>>(Wq, wqkvt,             D, H);
        transpose_cvt<<<g, 256, 0, stream>>>(Wk, wqkvt + (long long)H * D,     D, H);
        transpose_cvt<<<g, 256, 0, stream>>>(Wv, wqkvt + (long long)2 * H * D, D, H);
    }
    // 3. fused QKV projection: [B*S,3072] = xh @ Wqkv^T + b
    {
        dim3 g(N3 / 256, (B * S) / 256, 1);
        gemm256<true><<<g, 512, 0, stream>>>(xh, wqkvt, nullptr, qkv,
                                             D, D, D, N3, 0, 0, 0, 1.f, bq, bk, bv);
    }
    // 4. v slice -> vt [H][S] per batch
    {
        dim3 g(H / 64, S / 64, B);
        transpose_h64<<<g, 256, 0, stream>>>(qkv + 2 * H, (long long)S * N3, N3,
                                             vt, (long long)H * S, S);
    }
    // 5. scores = q k^T / 32 -> fp32 P
    {
        dim3 g(S / 256, S / 256, B);
        gemm256<false><<<g, 512, 0, stream>>>(qkv, qkv + H, outP, nullptr,
                                              D, N3, N3, S,
                                              (long long)S * N3, (long long)S * N3,
                                              (long long)S * S, 0.03125f,
                                              nullptr, nullptr, nullptr);
    }
    // 6. softmax rows; fp16 P overwrites dead q|k columns of qkv
    softmax_kernel<<<B * S, 256, 0, stream>>>(outP, qkv, S, N3);
    // 7. O = P v
    {
        dim3 g(H / 256, S / 256, B);
        gemm256<false><<<g, 512, 0, stream>>>(qkv, vt, outO, nullptr,
                                              S, N3, S, H,
                                              (long long)S * N3, (long long)H * S,
                                              (long long)S * H, 1.f,
                                              nullptr, nullptr, nullptr);
    }
}